// Round 4
// baseline (364.745 us; speedup 1.0000x reference)
//
#include <hip/hip_runtime.h>
#include <hip/hip_fp16.h>

// NCC loss, v11: fused kernel, D-ring moved from LDS to REGISTERS.
// v10 post-mortem: fusion correct (total 180.5->166.4, WRITE ~0) but kernel
// 93.3us at 36% occupancy — 77.8KB LDS caps 2 blocks/CU = 16 waves; barrier
// drains unhidden (VALU 43%, HBM 23%: latency-bound).
// v11: jj=(2r+half)%9 is compile-time const in the unrolled body, so the
// 9-slot fp16 ring lives in const-indexed register arrays (~27 VGPR, SROA).
// LDS 77.8->31.7KB; launch_bounds(512,6) forces VGPR<=85 -> 24 waves/CU.
// FCH 40->20 (960 blocks) to fill the new wave slots; D-halo 1.2->1.4x
// (FETCH ~206MB) is cheap at 23% HBM.
#define ND 2
#define DD 160
#define HH 192
#define WW 160
#define HW (HH * WW)
#define DHW (DD * HH * WW)

constexpr int TW  = 32;            // tile width  (outputs)
constexpr int TH  = 16;            // tile height (outputs) -> 512 columns
constexpr int HLO = TH + 8;        // 24 rows incl. H halo
constexpr int FCH = 20;            // d outputs per block
constexpr int NCH = DD / FCH;      // 8 chunks
constexpr int NSL = FCH + 8;       // 28 slices streamed
constexpr int NR  = NSL / 2;       // 14 rounds, 2 slices each

struct alignas(8) h4 { __half2 lo, hi; };

__device__ __forceinline__ void slide4(const float x[12], float S[4]) {
    float f = ((x[0] + x[1]) + (x[2] + x[3]))
            + ((x[4] + x[5]) + (x[6] + x[7])) + x[8];
    S[0] = f;
    f += x[9]  - x[0]; S[1] = f;
    f += x[10] - x[1]; S[2] = f;
    f += x[11] - x[2]; S[3] = f;
}

__global__ __launch_bounds__(512, 6)
void ncc_fused2(const float* __restrict__ I, const float* __restrict__ J,
                float* __restrict__ outp)
{
    // stage-A output: centered W-sums of (I,J,II,JJ) + IJ, 2 slices
    __shared__ float4 sws[2][HLO][TW + 1];          // 25,344 B
    __shared__ float  sw4[2][HLO][TW + 1];          //  6,336 B
    __shared__ float  wred[8];

    const int tid = threadIdx.x;
    const int w0  = blockIdx.x * TW;                // 0..128
    const int h0  = blockIdx.y * TH;                // 0..176
    const int z   = blockIdx.z;                     // 0..15
    const int n   = z >> 3;
    const int d0  = (z & 7) * FCH;

    // ---- stage-A role: 384 jobs = 2 slices x 24 rows x 8 groups ----
    const bool ajob = (tid < 384);
    const int  sl   = tid / 192;                    // slice-of-round (0/1)
    const int  rj   = tid - sl * 192;
    const int  arow = rj >> 3;                      // 0..23
    const int  awg  = rj & 7;                       // 0..7
    const int  agh  = h0 + arow - 4;
    const bool ahok = (agh >= 0) && (agh < HH);
    const int  agws = w0 + awg * 4 - 4;

    // ---- stage-B role: one (h,w) column per thread ----
    const int oh = tid >> 5;                        // 0..15
    const int ow = tid & 31;                        // 0..31
    const int h  = h0 + oh, w = w0 + ow;
    const float cW  = (float)(min(w + 4, WW - 1) - max(w - 4, 0) + 1);
    const float cH  = (float)(min(h + 4, HH - 1) - max(h - 4, 0) + 1);
    const float cHW = cW * cH;

    // D-ring: last 9 slices' centered HW-sums, fp16-packed in REGISTERS.
    // All accesses use compile-time jj -> SROA promotes to ~27 VGPRs.
    h4     ringp[9];
    __half rings[9];
    {
        h4 zz; zz.lo = __floats2half2_rn(0.f, 0.f); zz.hi = zz.lo;
        const __half z1 = __float2half(0.f);
        #pragma unroll
        for (int q = 0; q < 9; ++q) { ringp[q] = zz; rings[q] = z1; }
    }

    float run0 = 0.f, run1 = 0.f, run2 = 0.f, run3 = 0.f, run4 = 0.f;
    float acc = 0.f;
    const float inv = 1.0f / 729.0f;

    #pragma unroll 1
    for (int g = 0; g < 2; ++g) {                   // 2 x 9 = 18 >= NR
        #pragma unroll
        for (int r = 0; r < 9; ++r) {
            const int rr = g * 9 + r;
            if (rr < NR) {
                const int s0  = 2 * rr;
                const int dd0 = d0 - 4 + s0;
                // ---- stage A: W-sums for slices dd0, dd0+1 ----
                if (ajob) {
                    const int dd = dd0 + sl;
                    if (dd >= 0 && dd < DD) {
                        const int rbase = (n * DD + dd) * HW + agh * WW;
                        float a[12], b[12];
                        #pragma unroll
                        for (int c = 0; c < 3; ++c) {
                            const int gw = agws + 4 * c;
                            float4 va = make_float4(0.f, 0.f, 0.f, 0.f), vb = va;
                            if (ahok && gw >= 0 && gw < WW) {
                                va = *(const float4*)(I + rbase + gw);
                                vb = *(const float4*)(J + rbase + gw);
                                va.x -= 0.5f; va.y -= 0.5f; va.z -= 0.5f; va.w -= 0.5f;
                                vb.x -= 0.5f; vb.y -= 0.5f; vb.z -= 0.5f; vb.w -= 0.5f;
                            }
                            *(float4*)&a[4 * c] = va;
                            *(float4*)&b[4 * c] = vb;
                        }
                        float S0[4], S1[4], S2[4], S3[4], S4[4], f[12];
                        slide4(a, S0);
                        slide4(b, S1);
                        #pragma unroll
                        for (int i = 0; i < 12; ++i) f[i] = a[i] * a[i];
                        slide4(f, S2);
                        #pragma unroll
                        for (int i = 0; i < 12; ++i) f[i] = b[i] * b[i];
                        slide4(f, S3);
                        #pragma unroll
                        for (int i = 0; i < 12; ++i) f[i] = a[i] * b[i];
                        slide4(f, S4);
                        #pragma unroll
                        for (int t = 0; t < 4; ++t) {
                            sws[sl][arow][awg * 4 + t] =
                                make_float4(S0[t], S1[t], S2[t], S3[t]);
                            sw4[sl][arow][awg * 4 + t] = S4[t];
                        }
                    }
                }
                __syncthreads();
                // ---- stage B: HW-sum taps + fp16 reg-ring + cc ----
                #pragma unroll
                for (int half = 0; half < 2; ++half) {
                    const int s   = s0 + half;
                    const int ddx = dd0 + half;
                    float t0 = 0.f, t1 = 0.f, t2 = 0.f, t3 = 0.f, t4 = 0.f;
                    if (ddx >= 0 && ddx < DD) {
                        #pragma unroll
                        for (int q = 0; q < 9; ++q) {
                            const float4 v = sws[half][oh + q][ow];
                            t0 += v.x; t1 += v.y; t2 += v.z; t3 += v.w;
                            t4 += sw4[half][oh + q][ow];
                        }
                    }
                    // round to fp16 (same rounding as the proven ws format)
                    h4 nh;
                    nh.lo = __floats2half2_rn(t0, t1);
                    nh.hi = __floats2half2_rn(t2, t3);
                    const __half n4 = __float2half(t4);
                    const int jj = (2 * r + half) % 9;   // compile-time const
                    const h4     po = ringp[jj];
                    const __half p4 = rings[jj];
                    run0 += __half2float(nh.lo.x) - __half2float(po.lo.x);
                    run1 += __half2float(nh.lo.y) - __half2float(po.lo.y);
                    run2 += __half2float(nh.hi.x) - __half2float(po.hi.x);
                    run3 += __half2float(nh.hi.y) - __half2float(po.hi.y);
                    run4 += __half2float(n4)      - __half2float(p4);
                    ringp[jj] = nh;
                    rings[jj] = n4;
                    if (s >= 8) {
                        const int d = d0 + s - 8;
                        const float cD  = (float)(min(d + 4, DD - 1) - max(d - 4, 0) + 1);
                        const float cnt = cHW * cD;
                        // reconstruct uncentered box sums (exact algebra, from
                        // the verified pass2)
                        const float Is = run0 + 0.5f * cnt;
                        const float Js = run1 + 0.5f * cnt;
                        const float I2 = run2 + run0 + 0.25f * cnt;
                        const float J2 = run3 + run1 + 0.25f * cnt;
                        const float IJ = run4 + 0.5f * (run0 + run1) + 0.25f * cnt;
                        const float uI = Is * inv, uJ = Js * inv;
                        const float cross = IJ - uI * Js;
                        const float Iv = fmaxf(I2 - uI * Is, 1e-5f);
                        const float Jv = fmaxf(J2 - uJ * Js, 1e-5f);
                        acc += cross * cross / (Iv * Jv + 1e-5f);
                    }
                }
                __syncthreads();
            }
        }
    }

    // ---- block reduction, one fp32 atomic per block ----
    #pragma unroll
    for (int off = 32; off > 0; off >>= 1)
        acc += __shfl_down(acc, off, 64);
    const int lane = tid & 63, wid = tid >> 6;
    if (lane == 0) wred[wid] = acc;
    __syncthreads();
    if (tid == 0) {
        float s = 0.f;
        #pragma unroll
        for (int i = 0; i < 8; ++i) s += wred[i];
        atomicAdd(outp, -s);
    }
}

extern "C" void kernel_launch(void* const* d_in, const int* in_sizes, int n_in,
                              void* d_out, int out_size, void* d_ws, size_t ws_size,
                              hipStream_t stream)
{
    const float* I = (const float*)d_in[0];   // y_true
    const float* J = (const float*)d_in[1];   // y_pred
    float* out = (float*)d_out;

    hipMemsetAsync(out, 0, sizeof(float), stream);
    dim3 grid(WW / TW, HH / TH, ND * NCH);    // 5 x 12 x 16 = 960 blocks
    ncc_fused2<<<grid, 512, 0, stream>>>(I, J, out);
}

// Round 6
// 217.612 us; speedup vs baseline: 1.6761x; 1.6761x over previous
//
#include <hip/hip_runtime.h>
#include <hip/hip_fp16.h>

// NCC loss, v12 (resubmit — R5 bench failed on container acquisition, not
// the kernel): fused kernel, register D-ring, NO occupancy squeeze.
// v11 post-mortem: __launch_bounds__(512,6) forced VGPR->40 (counter),
// compiler spilled ring + stage-A buffers to scratch: WRITE 453MB,
// FETCH +206MB of scratch reads, VALU 14%, 297us. The register-ring idea
// was never actually tested — it was drowned by the forced spill.
// v12 = v11 with plain __launch_bounds__(512): natural VGPR ~80 ->
// 6 waves/SIMD = 24 waves/CU = 3 blocks/CU (LDS 31.7KB x3 = 95KB fits),
// 1.5x v10's wave count, zero spill, ring bank-traffic gone.
// FCH=20 kept: 960 blocks >= 768 resident slots at 3 blocks/CU.
#define ND 2
#define DD 160
#define HH 192
#define WW 160
#define HW (HH * WW)
#define DHW (DD * HH * WW)

constexpr int TW  = 32;            // tile width  (outputs)
constexpr int TH  = 16;            // tile height (outputs) -> 512 columns
constexpr int HLO = TH + 8;        // 24 rows incl. H halo
constexpr int FCH = 20;            // d outputs per block
constexpr int NCH = DD / FCH;      // 8 chunks
constexpr int NSL = FCH + 8;       // 28 slices streamed
constexpr int NR  = NSL / 2;       // 14 rounds, 2 slices each

struct alignas(8) h4 { __half2 lo, hi; };

__device__ __forceinline__ void slide4(const float x[12], float S[4]) {
    float f = ((x[0] + x[1]) + (x[2] + x[3]))
            + ((x[4] + x[5]) + (x[6] + x[7])) + x[8];
    S[0] = f;
    f += x[9]  - x[0]; S[1] = f;
    f += x[10] - x[1]; S[2] = f;
    f += x[11] - x[2]; S[3] = f;
}

__global__ __launch_bounds__(512)
void ncc_fused2(const float* __restrict__ I, const float* __restrict__ J,
                float* __restrict__ outp)
{
    // stage-A output: centered W-sums of (I,J,II,JJ) + IJ, 2 slices
    __shared__ float4 sws[2][HLO][TW + 1];          // 25,344 B
    __shared__ float  sw4[2][HLO][TW + 1];          //  6,336 B
    __shared__ float  wred[8];

    const int tid = threadIdx.x;
    const int w0  = blockIdx.x * TW;                // 0..128
    const int h0  = blockIdx.y * TH;                // 0..176
    const int z   = blockIdx.z;                     // 0..15
    const int n   = z >> 3;
    const int d0  = (z & 7) * FCH;

    // ---- stage-A role: 384 jobs = 2 slices x 24 rows x 8 groups ----
    const bool ajob = (tid < 384);
    const int  sl   = tid / 192;                    // slice-of-round (0/1)
    const int  rj   = tid - sl * 192;
    const int  arow = rj >> 3;                      // 0..23
    const int  awg  = rj & 7;                       // 0..7
    const int  agh  = h0 + arow - 4;
    const bool ahok = (agh >= 0) && (agh < HH);
    const int  agws = w0 + awg * 4 - 4;

    // ---- stage-B role: one (h,w) column per thread ----
    const int oh = tid >> 5;                        // 0..15
    const int ow = tid & 31;                        // 0..31
    const int h  = h0 + oh, w = w0 + ow;
    const float cW  = (float)(min(w + 4, WW - 1) - max(w - 4, 0) + 1);
    const float cH  = (float)(min(h + 4, HH - 1) - max(h - 4, 0) + 1);
    const float cHW = cW * cH;

    // D-ring: last 9 slices' centered HW-sums, fp16-packed in REGISTERS.
    // All accesses use compile-time jj -> SROA promotes to registers.
    h4     ringp[9];
    __half rings[9];
    {
        h4 zz; zz.lo = __floats2half2_rn(0.f, 0.f); zz.hi = zz.lo;
        const __half z1 = __float2half(0.f);
        #pragma unroll
        for (int q = 0; q < 9; ++q) { ringp[q] = zz; rings[q] = z1; }
    }

    float run0 = 0.f, run1 = 0.f, run2 = 0.f, run3 = 0.f, run4 = 0.f;
    float acc = 0.f;
    const float inv = 1.0f / 729.0f;

    #pragma unroll 1
    for (int g = 0; g < 2; ++g) {                   // 2 x 9 = 18 >= NR
        #pragma unroll
        for (int r = 0; r < 9; ++r) {
            const int rr = g * 9 + r;
            if (rr < NR) {
                const int s0  = 2 * rr;
                const int dd0 = d0 - 4 + s0;
                // ---- stage A: W-sums for slices dd0, dd0+1 ----
                if (ajob) {
                    const int dd = dd0 + sl;
                    if (dd >= 0 && dd < DD) {
                        const int rbase = (n * DD + dd) * HW + agh * WW;
                        float a[12], b[12];
                        #pragma unroll
                        for (int c = 0; c < 3; ++c) {
                            const int gw = agws + 4 * c;
                            float4 va = make_float4(0.f, 0.f, 0.f, 0.f), vb = va;
                            if (ahok && gw >= 0 && gw < WW) {
                                va = *(const float4*)(I + rbase + gw);
                                vb = *(const float4*)(J + rbase + gw);
                                va.x -= 0.5f; va.y -= 0.5f; va.z -= 0.5f; va.w -= 0.5f;
                                vb.x -= 0.5f; vb.y -= 0.5f; vb.z -= 0.5f; vb.w -= 0.5f;
                            }
                            *(float4*)&a[4 * c] = va;
                            *(float4*)&b[4 * c] = vb;
                        }
                        float S0[4], S1[4], S2[4], S3[4], S4[4], f[12];
                        slide4(a, S0);
                        slide4(b, S1);
                        #pragma unroll
                        for (int i = 0; i < 12; ++i) f[i] = a[i] * a[i];
                        slide4(f, S2);
                        #pragma unroll
                        for (int i = 0; i < 12; ++i) f[i] = b[i] * b[i];
                        slide4(f, S3);
                        #pragma unroll
                        for (int i = 0; i < 12; ++i) f[i] = a[i] * b[i];
                        slide4(f, S4);
                        #pragma unroll
                        for (int t = 0; t < 4; ++t) {
                            sws[sl][arow][awg * 4 + t] =
                                make_float4(S0[t], S1[t], S2[t], S3[t]);
                            sw4[sl][arow][awg * 4 + t] = S4[t];
                        }
                    }
                }
                __syncthreads();
                // ---- stage B: HW-sum taps + fp16 reg-ring + cc ----
                #pragma unroll
                for (int half = 0; half < 2; ++half) {
                    const int s   = s0 + half;
                    const int ddx = dd0 + half;
                    float t0 = 0.f, t1 = 0.f, t2 = 0.f, t3 = 0.f, t4 = 0.f;
                    if (ddx >= 0 && ddx < DD) {
                        #pragma unroll
                        for (int q = 0; q < 9; ++q) {
                            const float4 v = sws[half][oh + q][ow];
                            t0 += v.x; t1 += v.y; t2 += v.z; t3 += v.w;
                            t4 += sw4[half][oh + q][ow];
                        }
                    }
                    // round to fp16 (same rounding as the proven ws format)
                    h4 nh;
                    nh.lo = __floats2half2_rn(t0, t1);
                    nh.hi = __floats2half2_rn(t2, t3);
                    const __half n4 = __float2half(t4);
                    const int jj = (2 * r + half) % 9;   // compile-time const
                    const h4     po = ringp[jj];
                    const __half p4 = rings[jj];
                    run0 += __half2float(nh.lo.x) - __half2float(po.lo.x);
                    run1 += __half2float(nh.lo.y) - __half2float(po.lo.y);
                    run2 += __half2float(nh.hi.x) - __half2float(po.hi.x);
                    run3 += __half2float(nh.hi.y) - __half2float(po.hi.y);
                    run4 += __half2float(n4)      - __half2float(p4);
                    ringp[jj] = nh;
                    rings[jj] = n4;
                    if (s >= 8) {
                        const int d = d0 + s - 8;
                        const float cD  = (float)(min(d + 4, DD - 1) - max(d - 4, 0) + 1);
                        const float cnt = cHW * cD;
                        // reconstruct uncentered box sums (exact algebra, from
                        // the verified pass2)
                        const float Is = run0 + 0.5f * cnt;
                        const float Js = run1 + 0.5f * cnt;
                        const float I2 = run2 + run0 + 0.25f * cnt;
                        const float J2 = run3 + run1 + 0.25f * cnt;
                        const float IJ = run4 + 0.5f * (run0 + run1) + 0.25f * cnt;
                        const float uI = Is * inv, uJ = Js * inv;
                        const float cross = IJ - uI * Js;
                        const float Iv = fmaxf(I2 - uI * Is, 1e-5f);
                        const float Jv = fmaxf(J2 - uJ * Js, 1e-5f);
                        acc += cross * cross / (Iv * Jv + 1e-5f);
                    }
                }
                __syncthreads();
            }
        }
    }

    // ---- block reduction, one fp32 atomic per block ----
    #pragma unroll
    for (int off = 32; off > 0; off >>= 1)
        acc += __shfl_down(acc, off, 64);
    const int lane = tid & 63, wid = tid >> 6;
    if (lane == 0) wred[wid] = acc;
    __syncthreads();
    if (tid == 0) {
        float s = 0.f;
        #pragma unroll
        for (int i = 0; i < 8; ++i) s += wred[i];
        atomicAdd(outp, -s);
    }
}

extern "C" void kernel_launch(void* const* d_in, const int* in_sizes, int n_in,
                              void* d_out, int out_size, void* d_ws, size_t ws_size,
                              hipStream_t stream)
{
    const float* I = (const float*)d_in[0];   // y_true
    const float* J = (const float*)d_in[1];   // y_pred
    float* out = (float*)d_out;

    hipMemsetAsync(out, 0, sizeof(float), stream);
    dim3 grid(WW / TW, HH / TH, ND * NCH);    // 5 x 12 x 16 = 960 blocks
    ncc_fused2<<<grid, 512, 0, stream>>>(I, J, out);
}